// Round 4
// baseline (1082.823 us; speedup 1.0000x reference)
//
#include <hip/hip_runtime.h>

static constexpr int MM  = 90000;  // cells (fixed by setup_inputs)
static constexpr int TT  = 150;    // steps (fixed by setup_inputs)
static constexpr int BS  = 512;    // threads per block (8 waves)
static constexpr int CPT = 4;      // cells per thread
static constexpr int CPB = BS * CPT;                 // 2048 cells per block
static constexpr int NB  = (MM + CPB - 1) / CPB;     // 44 blocks
static constexpr int WPB = BS / 64;                  // 8 waves per block
static constexpr int NW  = NB * WPB;                 // 352 wave-slots
static constexpr int SLOTS = 384;                    // padded row; [NW..SLOTS) preset to 1u

// Per-step publish slots (re-initialized by init_ws_kernel at EVERY launch —
// __device__ globals persist across launches). All cross-block traffic is
// relaxed agent-scope (L2-bypassing, IF-coherent) loads/stores of
// self-flagging words -> no fences / cache maintenance anywhere.
__device__ unsigned int g_wmax[TT + 1][SLOTS];          // bits of per-wave max s (>0)
__device__ unsigned long long g_edge[TT + 1][NB][2];    // packed (A,Q) block-edge state

__device__ __forceinline__ float softplus_f(float x) {
    return fmaxf(x, 0.0f) + log1pf(expf(-fabsf(x)));
}
__device__ __forceinline__ unsigned long long packAQ(float A, float Q) {
    return ((unsigned long long)__float_as_uint(Q) << 32) | (unsigned long long)__float_as_uint(A);
}

__global__ void init_ws_kernel() {
    int i = blockIdx.x * blockDim.x + threadIdx.x;
    int stride = gridDim.x * blockDim.x;
    unsigned int* pb = &g_wmax[0][0];
    for (int j = i; j < (TT + 1) * SLOTS; j += stride)
        pb[j] = ((j % SLOTS) < NW) ? 0u : 1u;   // sentinel pad slots always "arrived"
    unsigned long long* pe = &g_edge[0][0][0];
    for (int j = i; j < (TT + 1) * NB * 2; j += stride) pe[j] = 0ull;
}

__global__ void __launch_bounds__(BS) sim_kernel(
    const float* __restrict__ Rs,
    const float* __restrict__ sim_dat,
    const float* __restrict__ sdc,
    const float* __restrict__ inflow,
    float* __restrict__ out)
{
    __shared__ float sE[2][WPB][2][3];   // [buf][wave][left/right edge cell][A,Q,F]

    const int b    = blockIdx.x;
    const int tid  = threadIdx.x;
    const int wv   = tid >> 6;
    const int lane = tid & 63;
    const int widx = b * WPB + wv;
    const int base = b * CPB + tid * CPT;   // first of this thread's 4 contiguous cells

    // ---- per-cell constants & initial state (registers for the whole sim) ----
    float A[CPT], Q[CPT], A0v[CPT], bet[CPT], cbv[CPT], k2v[CPT];
    float sq[CPT], FQ[CPT];
    bool  act[CPT];
    #pragma unroll
    for (int c = 0; c < CPT; ++c) {
        int i = base + c;
        act[c] = (i < MM);
        if (act[c]) {
            A[c]   = fmaxf(sim_dat[i], 1e-6f);
            Q[c]   = 0.1f * sim_dat[MM + i];
            A0v[c] = sdc[i] + 0.5f;
            bet[c] = sdc[MM + i] + 1.0f;
        } else { A[c] = 1.0f; Q[c] = 0.0f; A0v[c] = 1.0f; bet[c] = 1.0f; }
        cbv[c] = (0.5f * bet[c]) / 1060.0f;     // (0.5*beta)/RHO   (ref op order)
        k2v[c] = bet[c] / (3180.0f * A0v[c]);   // beta/(3*RHO*A0), 3*1060=3180 exact
    }
    const bool isStart = (base == 0) | (base == 30000) | (base == 60000);          // cell 0
    const bool isEnd   = (base + 3 == 29999) | (base + 3 == 59999) | (base + 3 == 89999); // cell 3
    int midSlot = (base == 15000) ? 0 : (base == 45000) ? 1 : (base == 75000) ? 2 : -1;   // cell 0
    float Rtot = 1.0f;
    if (isEnd) {
        int i3 = base + 3;
        float R1 = sdc[7 * MM + i3] + 0.5f;
        float R2 = sdc[8 * MM + i3] + 0.5f;
        if (i3 == 59999)      { R1 *= softplus_f(Rs[0]); R2 *= softplus_f(Rs[1]); }
        else if (i3 == 89999) { R1 *= softplus_f(Rs[2]); R2 *= softplus_f(Rs[3]); }
        Rtot = R1 + R2;
    }

    // Block-halo roles
    const bool needEdgeL = (wv == 0 && lane == 0 && b > 0);
    const bool needEdgeR = (wv == WPB - 1 && lane == 63 && b < NB - 1);
    const int  eoff = needEdgeL ? ((b - 1) * 2 + 1) : (needEdgeR ? ((b + 1) * 2) : -1);
    float A0h = 1.0f, kh = 1.0f;   // halo-neighbor constants for F recompute
    if (needEdgeL) { int j = base - 1;   A0h = sdc[j] + 0.5f; kh = (sdc[MM + j] + 1.0f) / (3180.0f * A0h); }
    if (needEdgeR) { int j = base + CPT; A0h = sdc[j] + 0.5f; kh = (sdc[MM + j] + 1.0f) / (3180.0f * A0h); }
    const bool pubL = (tid == 0) && (b > 0);
    const bool pubR = (tid == BS - 1) && (b < NB - 1);

    // ---- initial derived state + first publish (t = 0) ----
    float s4 = 0.0f;
    #pragma unroll
    for (int c = 0; c < CPT; ++c) {
        sq[c] = sqrtf(A[c] / A0v[c]);
        float u  = Q[c] / A[c];
        float cc = sqrtf(cbv[c] * sq[c]);
        float s  = act[c] ? (fabsf(u) + cc) : 0.0f;
        FQ[c] = Q[c] * u + k2v[c] * A[c] * sq[c];
        s4 = fmaxf(s4, s);
    }
    if (pubL) __hip_atomic_store(&g_edge[0][b][0], packAQ(A[0], Q[0]), __ATOMIC_RELAXED, __HIP_MEMORY_SCOPE_AGENT);
    if (pubR) __hip_atomic_store(&g_edge[0][b][1], packAQ(A[3], Q[3]), __ATOMIC_RELAXED, __HIP_MEMORY_SCOPE_AGENT);
    {
        float mm = s4;
        #pragma unroll
        for (int off = 32; off > 0; off >>= 1) mm = fmaxf(mm, __shfl_xor(mm, off, 64));
        if (lane == 0)      { sE[0][wv][0][0] = A[0]; sE[0][wv][0][1] = Q[0]; sE[0][wv][0][2] = FQ[0]; }
        else if (lane == 63){ sE[0][wv][1][0] = A[3]; sE[0][wv][1][1] = Q[3]; sE[0][wv][1][2] = FQ[3]; }
        asm volatile("s_waitcnt lgkmcnt(0)" ::: "memory");   // LDS stage visible before flag
        if (lane == 0)
            __hip_atomic_store(&g_wmax[0][widx], __float_as_uint(mm), __ATOMIC_RELAXED, __HIP_MEMORY_SCOPE_AGENT);
    }

    for (int t = 0; t < TT; ++t) {
        const int buf = t & 1, nbuf = buf ^ 1;

        // ---- wave-autonomous barrier: poll all wave slots (+ own halo word) ----
        float ml;
        unsigned long long ev = 1ull;
        const unsigned int* row = &g_wmax[t][0];
        const unsigned long long* erow = &g_edge[t][0][0];
        for (;;) {
            bool ok = true;
            ml = 0.0f;
            #pragma unroll
            for (int j = 0; j < SLOTS / 64; ++j) {
                unsigned int x = __hip_atomic_load(row + lane + 64 * j,
                                                   __ATOMIC_RELAXED, __HIP_MEMORY_SCOPE_AGENT);
                ok &= (x != 0u);
                ml = fmaxf(ml, __uint_as_float(x));
            }
            if (eoff >= 0) {
                ev = __hip_atomic_load(erow + eoff, __ATOMIC_RELAXED, __HIP_MEMORY_SCOPE_AGENT);
                ok &= (ev != 0ull);
            }
            if (__all(ok)) break;
        }
        #pragma unroll
        for (int off = 32; off > 0; off >>= 1) ml = fmaxf(ml, __shfl_xor(ml, off, 64));
        const float smax = ml;

        // ---- step t ----
        const float dt  = ((float)(0.9 * 0.001)) / smax;   // CCFL*DX/smax (ref op order)
        const float lam = dt / 0.001f;                     // dt/DX
        if (midSlot >= 0) out[t * 3 + midSlot] = bet[0] * (sq[0] - 1.0f);

        // neighbor exchange: in-wave via shfl, wave-edge via LDS, block-edge via g_edge
        float Am = __shfl_up(A[3], 1, 64), Qm = __shfl_up(Q[3], 1, 64), Fm = __shfl_up(FQ[3], 1, 64);
        float Ap = __shfl_down(A[0], 1, 64), Qp = __shfl_down(Q[0], 1, 64), Fp = __shfl_down(FQ[0], 1, 64);
        if (lane == 0) {
            if (wv > 0) { Am = sE[buf][wv-1][1][0]; Qm = sE[buf][wv-1][1][1]; Fm = sE[buf][wv-1][1][2]; }
            else if (b > 0) {
                Am = __uint_as_float((unsigned int)ev);
                Qm = __uint_as_float((unsigned int)(ev >> 32));
                float sqm = sqrtf(Am / A0h);
                float um  = Qm / Am;
                Fm = Qm * um + kh * Am * sqm;
            }
        }
        if (lane == 63) {
            if (wv < WPB - 1) { Ap = sE[buf][wv+1][0][0]; Qp = sE[buf][wv+1][0][1]; Fp = sE[buf][wv+1][0][2]; }
            else if (b < NB - 1) {
                Ap = __uint_as_float((unsigned int)ev);
                Qp = __uint_as_float((unsigned int)(ev >> 32));
                float sqp = sqrtf(Ap / A0h);
                float up  = Qp / Ap;
                Fp = Qp * up + kh * Ap * sqp;
            }
        }

        float An[CPT], Qn[CPT];
        #pragma unroll
        for (int c = 0; c < CPT; ++c) {
            int i = base + c;
            float Al = (c == 0) ? Am : A[c-1], Ql = (c == 0) ? Qm : Q[c-1], Fl = (c == 0) ? Fm : FQ[c-1];
            float Ar = (c == 3) ? Ap : A[c+1], Qr = (c == 3) ? Qp : Q[c+1], Fr = (c == 3) ? Fp : FQ[c+1];
            if (act[c] && i > 0 && i < MM - 1) {
                float fhA_r = 0.5f * (Q[c] + Qr) - 0.5f * smax * (Ar - A[c]);
                float fhA_l = 0.5f * (Ql + Q[c]) - 0.5f * smax * (A[c] - Al);
                float fhQ_r = 0.5f * (FQ[c] + Fr) - 0.5f * smax * (Qr - Q[c]);
                float fhQ_l = 0.5f * (Fl + FQ[c]) - 0.5f * smax * (Q[c] - Ql);
                An[c] = A[c] - lam * (fhA_r - fhA_l);
                Qn[c] = Q[c] - lam * (fhQ_r - fhQ_l);
            } else { An[c] = A[c]; Qn[c] = Q[c]; }
        }
        if (isStart) Qn[0] = inflow[t];
        if (isEnd)   Qn[3] = bet[3] * (sq[3] - 1.0f) / Rtot;
        #pragma unroll
        for (int c = 0; c < CPT; ++c) { A[c] = fmaxf(An[c], 1e-6f); Q[c] = Qn[c]; }

        // publish next-step block edges ASAP (self-flagging; polled directly by reader)
        if (pubL) __hip_atomic_store(&g_edge[t+1][b][0], packAQ(A[0], Q[0]), __ATOMIC_RELAXED, __HIP_MEMORY_SCOPE_AGENT);
        if (pubR) __hip_atomic_store(&g_edge[t+1][b][1], packAQ(A[3], Q[3]), __ATOMIC_RELAXED, __HIP_MEMORY_SCOPE_AGENT);

        // derived state for t+1 + wave max
        s4 = 0.0f;
        #pragma unroll
        for (int c = 0; c < CPT; ++c) {
            sq[c] = sqrtf(A[c] / A0v[c]);
            float u  = Q[c] / A[c];
            float cc = sqrtf(cbv[c] * sq[c]);
            float s  = act[c] ? (fabsf(u) + cc) : 0.0f;
            FQ[c] = Q[c] * u + k2v[c] * A[c] * sq[c];
            s4 = fmaxf(s4, s);
        }
        float mm = s4;
        #pragma unroll
        for (int off = 32; off > 0; off >>= 1) mm = fmaxf(mm, __shfl_xor(mm, off, 64));
        if (lane == 0)      { sE[nbuf][wv][0][0] = A[0]; sE[nbuf][wv][0][1] = Q[0]; sE[nbuf][wv][0][2] = FQ[0]; }
        else if (lane == 63){ sE[nbuf][wv][1][0] = A[3]; sE[nbuf][wv][1][1] = Q[3]; sE[nbuf][wv][1][2] = FQ[3]; }
        asm volatile("s_waitcnt lgkmcnt(0)" ::: "memory");   // LDS stage before flag
        if (lane == 0)
            __hip_atomic_store(&g_wmax[t+1][widx], __float_as_uint(mm), __ATOMIC_RELAXED, __HIP_MEMORY_SCOPE_AGENT);
    }
}

extern "C" void kernel_launch(void* const* d_in, const int* in_sizes, int n_in,
                              void* d_out, int out_size, void* d_ws, size_t ws_size,
                              hipStream_t stream) {
    (void)in_sizes; (void)n_in; (void)d_ws; (void)ws_size; (void)out_size;

    const float* Rs      = (const float*)d_in[0];
    const float* sim_dat = (const float*)d_in[1];
    const float* sdc     = (const float*)d_in[2];
    const float* inflow  = (const float*)d_in[3];
    float* out = (float*)d_out;

    hipLaunchKernelGGL(init_ws_kernel, dim3(120), dim3(256), 0, stream);

    // 44 blocks x 8 waves, ~0.4 KB LDS, modest VGPR -> trivially co-resident.
    hipLaunchKernelGGL(sim_kernel, dim3(NB), dim3(BS), 0, stream,
                       Rs, sim_dat, sdc, inflow, out);
}

// Round 5
// 833.458 us; speedup vs baseline: 1.2992x; 1.2992x over previous
//
#include <hip/hip_runtime.h>

static constexpr int MM  = 90000;  // cells (fixed by setup_inputs)
static constexpr int TT  = 150;    // steps (fixed by setup_inputs)
static constexpr int BS  = 1024;   // threads per block (16 waves)
static constexpr int CPT = 2;      // cells per thread
static constexpr int CPB = BS * CPT;               // 2048 cells per block
static constexpr int NB  = (MM + CPB - 1) / CPB;   // 44 blocks
static constexpr int WPB = BS / 64;                // 16 waves per block

// Per-step publish slots (re-initialized by init_ws_kernel at EVERY launch).
// All cross-block traffic is relaxed agent-scope (L2-bypassing, IF-coherent)
// loads/stores of self-flagging words -> no fences / cache maintenance.
__device__ unsigned int g_bmax[TT + 1][64];           // per-block max s bits; [NB..64) sentinel 1u
__device__ unsigned long long g_edge[TT + 1][NB][2];  // packed (A,Q) block-edge state

__device__ __forceinline__ float softplus_f(float x) {
    return fmaxf(x, 0.0f) + log1pf(expf(-fabsf(x)));
}
__device__ __forceinline__ unsigned long long packAQ(float A, float Q) {
    return ((unsigned long long)__float_as_uint(Q) << 32) | (unsigned long long)__float_as_uint(A);
}

__global__ void init_ws_kernel() {
    int i = blockIdx.x * blockDim.x + threadIdx.x;
    int stride = gridDim.x * blockDim.x;
    unsigned int* pb = &g_bmax[0][0];
    for (int j = i; j < (TT + 1) * 64; j += stride)
        pb[j] = ((j & 63) < NB) ? 0u : 1u;      // sentinel pads always "arrived"
    unsigned long long* pe = &g_edge[0][0][0];
    for (int j = i; j < (TT + 1) * NB * 2; j += stride) pe[j] = 0ull;
}

__global__ void __launch_bounds__(BS) sim_kernel(
    const float* __restrict__ Rs,
    const float* __restrict__ sim_dat,
    const float* __restrict__ sdc,
    const float* __restrict__ inflow,
    float* __restrict__ out)
{
    __shared__ float        sE[2][WPB][2][3];   // [parity][wave][L/R edge cell][A,Q,F]
    __shared__ unsigned int lds_bmax[TT + 1];   // per-step block max (atomicMax target)
    __shared__ unsigned int lds_cnt[TT + 1];    // per-step wave-arrival counter
    __shared__ unsigned int s_smax[TT + 1];     // per-step final smax bits (broadcast word)

    const int b    = blockIdx.x;
    const int tid  = threadIdx.x;
    const int wv   = tid >> 6;
    const int lane = tid & 63;
    const int base = b * CPB + tid * CPT;       // this thread's 2 contiguous cells

    // ---- zero per-step LDS arrays (once, before any use) ----
    for (int j = tid; j < TT + 1; j += BS) { lds_bmax[j] = 0u; lds_cnt[j] = 0u; s_smax[j] = 0u; }

    // ---- per-cell constants & initial state (registers for the whole sim) ----
    float A[CPT], Q[CPT], A0v[CPT], bet[CPT], cbv[CPT], k2v[CPT], sq[CPT], FQ[CPT];
    bool  act[CPT];
    #pragma unroll
    for (int c = 0; c < CPT; ++c) {
        int i = base + c;
        act[c] = (i < MM);
        if (act[c]) {
            A[c]   = fmaxf(sim_dat[i], 1e-6f);
            Q[c]   = 0.1f * sim_dat[MM + i];
            A0v[c] = sdc[i] + 0.5f;
            bet[c] = sdc[MM + i] + 1.0f;
        } else { A[c] = 1.0f; Q[c] = 0.0f; A0v[c] = 1.0f; bet[c] = 1.0f; }
        cbv[c] = (0.5f * bet[c]) / 1060.0f;     // (0.5*beta)/RHO   (ref op order)
        k2v[c] = bet[c] / (3180.0f * A0v[c]);   // beta/(3*RHO*A0), 3*1060=3180 exact
    }
    const bool isStart = (base == 0) | (base == 30000) | (base == 60000);               // cell 0
    const bool isEnd   = (base + 1 == 29999) | (base + 1 == 59999) | (base + 1 == 89999); // cell 1
    const int midSlot = (base == 15000) ? 0 : (base == 45000) ? 1 : (base == 75000) ? 2 : -1;
    float Rtot = 1.0f;
    if (isEnd) {
        int i1 = base + 1;
        float R1 = sdc[7 * MM + i1] + 0.5f;
        float R2 = sdc[8 * MM + i1] + 0.5f;
        if (i1 == 59999)      { R1 *= softplus_f(Rs[0]); R2 *= softplus_f(Rs[1]); }
        else if (i1 == 89999) { R1 *= softplus_f(Rs[2]); R2 *= softplus_f(Rs[3]); }
        Rtot = R1 + R2;
    }

    // Block-halo roles (exactly one reader lane per edge; reader also polls the word)
    const bool needEdgeL = (wv == 0) && (lane == 0) && (b > 0);
    const bool needEdgeR = (wv == WPB - 1) && (lane == 63) && (b < NB - 1);
    float A0h = 1.0f, kh = 1.0f;
    if (needEdgeL) { int j = base - 1;   A0h = sdc[j] + 0.5f; kh = (sdc[MM + j] + 1.0f) / (3180.0f * A0h); }
    if (needEdgeR) { int j = base + CPT; A0h = sdc[j] + 0.5f; kh = (sdc[MM + j] + 1.0f) / (3180.0f * A0h); }
    const bool pubL = (tid == 0) && (b > 0);
    const bool pubR = (tid == BS - 1) && (b < NB - 1);

    __syncthreads();   // LDS zero-init visible to all waves (only barrier in the kernel)

    // ---- initial derived state + t=0 contribution ----
    float s2 = 0.0f;
    #pragma unroll
    for (int c = 0; c < CPT; ++c) {
        sq[c] = sqrtf(A[c] / A0v[c]);
        float u  = Q[c] / A[c];
        float cc = sqrtf(cbv[c] * sq[c]);
        FQ[c] = Q[c] * u + k2v[c] * A[c] * sq[c];
        s2 = fmaxf(s2, act[c] ? (fabsf(u) + cc) : 0.0f);
    }
    if (pubL) __hip_atomic_store(&g_edge[0][b][0], packAQ(A[0], Q[0]), __ATOMIC_RELAXED, __HIP_MEMORY_SCOPE_AGENT);
    if (pubR) __hip_atomic_store(&g_edge[0][b][1], packAQ(A[1], Q[1]), __ATOMIC_RELAXED, __HIP_MEMORY_SCOPE_AGENT);
    {
        float mm = s2;
        #pragma unroll
        for (int off = 32; off > 0; off >>= 1) mm = fmaxf(mm, __shfl_xor(mm, off, 64));
        if (lane == 0)       { sE[0][wv][0][0] = A[0]; sE[0][wv][0][1] = Q[0]; sE[0][wv][0][2] = FQ[0]; }
        else if (lane == 63) { sE[0][wv][1][0] = A[1]; sE[0][wv][1][1] = Q[1]; sE[0][wv][1][2] = FQ[1]; }
        asm volatile("s_waitcnt lgkmcnt(0)" ::: "memory");     // edge stage before arrival flag
        if (lane == 0) {
            atomicMax(&lds_bmax[0], __float_as_uint(mm));
            asm volatile("s_waitcnt lgkmcnt(0)" ::: "memory"); // max committed before count
            unsigned int old = atomicAdd(&lds_cnt[0], 1u);
            if (old == WPB - 1) {
                unsigned int bm = __hip_atomic_load(&lds_bmax[0], __ATOMIC_RELAXED, __HIP_MEMORY_SCOPE_WORKGROUP);
                __hip_atomic_store(&g_bmax[0][b], bm, __ATOMIC_RELAXED, __HIP_MEMORY_SCOPE_AGENT);
            }
        }
    }

    for (int t = 0; t < TT; ++t) {
        const int par = t & 1, npar = par ^ 1;

        // ================= step-t barrier (no __syncthreads) =================
        float smax;
        unsigned long long ev = 1ull;
        if (wv == 0) {
            // polling wave: one coalesced 4-line load per iteration (+1 word, lane 0)
            const unsigned int* row = &g_bmax[t][0];
            unsigned int x;
            for (;;) {
                x = __hip_atomic_load(row + lane, __ATOMIC_RELAXED, __HIP_MEMORY_SCOPE_AGENT);
                bool ok = (x != 0u);
                if (needEdgeL) {
                    ev = __hip_atomic_load(&g_edge[t][b - 1][1], __ATOMIC_RELAXED, __HIP_MEMORY_SCOPE_AGENT);
                    ok &= (ev != 0ull);
                }
                if (__all(ok)) break;
            }
            float ml = __uint_as_float(x);
            #pragma unroll
            for (int off = 32; off > 0; off >>= 1) ml = fmaxf(ml, __shfl_xor(ml, off, 64));
            smax = ml;
            if (lane == 0)
                __hip_atomic_store(&s_smax[t], __float_as_uint(ml), __ATOMIC_RELAXED, __HIP_MEMORY_SCOPE_WORKGROUP);
        } else {
            // spinning waves: LDS word only (+1 global word for the right-edge lane)
            unsigned int x;
            for (;;) {
                x = __hip_atomic_load(&s_smax[t], __ATOMIC_RELAXED, __HIP_MEMORY_SCOPE_WORKGROUP);
                bool ok = (x != 0u);
                if (needEdgeR) {
                    ev = __hip_atomic_load(&g_edge[t][b + 1][0], __ATOMIC_RELAXED, __HIP_MEMORY_SCOPE_AGENT);
                    ok &= (ev != 0ull);
                }
                if (__all(ok)) break;
            }
            smax = __uint_as_float(x);
        }

        // ========================== step t ==========================
        const float dt  = ((float)(0.9 * 0.001)) / smax;   // CCFL*DX/smax (ref op order)
        const float lam = dt / 0.001f;                     // dt/DX
        if (midSlot >= 0) out[t * 3 + midSlot] = bet[0] * (sq[0] - 1.0f);

        // neighbors: in-wave shfl; wave-edge via sE[par]; block-edge via ev
        float Am = __shfl_up(A[1], 1, 64),  Qm = __shfl_up(Q[1], 1, 64),  Fm = __shfl_up(FQ[1], 1, 64);
        float Ap = __shfl_down(A[0], 1, 64), Qp = __shfl_down(Q[0], 1, 64), Fp = __shfl_down(FQ[0], 1, 64);
        if (lane == 0) {
            if (wv > 0) { Am = sE[par][wv-1][1][0]; Qm = sE[par][wv-1][1][1]; Fm = sE[par][wv-1][1][2]; }
            else if (b > 0) {
                Am = __uint_as_float((unsigned int)ev);
                Qm = __uint_as_float((unsigned int)(ev >> 32));
                float sqm = sqrtf(Am / A0h), um = Qm / Am;
                Fm = Qm * um + kh * Am * sqm;
            }
        }
        if (lane == 63) {
            if (wv < WPB - 1) { Ap = sE[par][wv+1][0][0]; Qp = sE[par][wv+1][0][1]; Fp = sE[par][wv+1][0][2]; }
            else if (b < NB - 1) {
                Ap = __uint_as_float((unsigned int)ev);
                Qp = __uint_as_float((unsigned int)(ev >> 32));
                float sqp = sqrtf(Ap / A0h), up = Qp / Ap;
                Fp = Qp * up + kh * Ap * sqp;
            }
        }

        float An[CPT], Qn[CPT];
        #pragma unroll
        for (int c = 0; c < CPT; ++c) {
            int i = base + c;
            float Al = (c == 0) ? Am : A[0],  Ql = (c == 0) ? Qm : Q[0],  Fl = (c == 0) ? Fm : FQ[0];
            float Ar = (c == 1) ? Ap : A[1],  Qr = (c == 1) ? Qp : Q[1],  Fr = (c == 1) ? Fp : FQ[1];
            if (act[c] && i > 0 && i < MM - 1) {
                float fhA_r = 0.5f * (Q[c] + Qr) - 0.5f * smax * (Ar - A[c]);
                float fhA_l = 0.5f * (Ql + Q[c]) - 0.5f * smax * (A[c] - Al);
                float fhQ_r = 0.5f * (FQ[c] + Fr) - 0.5f * smax * (Qr - Q[c]);
                float fhQ_l = 0.5f * (Fl + FQ[c]) - 0.5f * smax * (Q[c] - Ql);
                An[c] = A[c] - lam * (fhA_r - fhA_l);
                Qn[c] = Q[c] - lam * (fhQ_r - fhQ_l);
            } else { An[c] = A[c]; Qn[c] = Q[c]; }
        }
        if (isStart) Qn[0] = inflow[t];
        if (isEnd)   Qn[1] = bet[1] * (sq[1] - 1.0f) / Rtot;
        #pragma unroll
        for (int c = 0; c < CPT; ++c) { A[c] = fmaxf(An[c], 1e-6f); Q[c] = Qn[c]; }

        // block-edge publish for t+1 ASAP (self-flagging; hides under barrier)
        if (pubL) __hip_atomic_store(&g_edge[t+1][b][0], packAQ(A[0], Q[0]), __ATOMIC_RELAXED, __HIP_MEMORY_SCOPE_AGENT);
        if (pubR) __hip_atomic_store(&g_edge[t+1][b][1], packAQ(A[1], Q[1]), __ATOMIC_RELAXED, __HIP_MEMORY_SCOPE_AGENT);

        // derived state for t+1, wave max, stage edges, contribute to barrier t+1
        s2 = 0.0f;
        #pragma unroll
        for (int c = 0; c < CPT; ++c) {
            sq[c] = sqrtf(A[c] / A0v[c]);
            float u  = Q[c] / A[c];
            float cc = sqrtf(cbv[c] * sq[c]);
            FQ[c] = Q[c] * u + k2v[c] * A[c] * sq[c];
            s2 = fmaxf(s2, act[c] ? (fabsf(u) + cc) : 0.0f);
        }
        float mm = s2;
        #pragma unroll
        for (int off = 32; off > 0; off >>= 1) mm = fmaxf(mm, __shfl_xor(mm, off, 64));
        if (lane == 0)       { sE[npar][wv][0][0] = A[0]; sE[npar][wv][0][1] = Q[0]; sE[npar][wv][0][2] = FQ[0]; }
        else if (lane == 63) { sE[npar][wv][1][0] = A[1]; sE[npar][wv][1][1] = Q[1]; sE[npar][wv][1][2] = FQ[1]; }
        asm volatile("s_waitcnt lgkmcnt(0)" ::: "memory");     // edge stage before arrival flag
        if (lane == 0) {
            atomicMax(&lds_bmax[t + 1], __float_as_uint(mm));
            asm volatile("s_waitcnt lgkmcnt(0)" ::: "memory"); // max committed before count
            unsigned int old = atomicAdd(&lds_cnt[t + 1], 1u);
            if (old == WPB - 1) {   // 16th arriver owns the complete block max -> publish
                unsigned int bm = __hip_atomic_load(&lds_bmax[t + 1], __ATOMIC_RELAXED, __HIP_MEMORY_SCOPE_WORKGROUP);
                __hip_atomic_store(&g_bmax[t + 1][b], bm, __ATOMIC_RELAXED, __HIP_MEMORY_SCOPE_AGENT);
            }
        }
    }
}

extern "C" void kernel_launch(void* const* d_in, const int* in_sizes, int n_in,
                              void* d_out, int out_size, void* d_ws, size_t ws_size,
                              hipStream_t stream) {
    (void)in_sizes; (void)n_in; (void)d_ws; (void)ws_size; (void)out_size;

    const float* Rs      = (const float*)d_in[0];
    const float* sim_dat = (const float*)d_in[1];
    const float* sdc     = (const float*)d_in[2];
    const float* inflow  = (const float*)d_in[3];
    float* out = (float*)d_out;

    hipLaunchKernelGGL(init_ws_kernel, dim3(120), dim3(256), 0, stream);

    // 44 blocks x 16 waves, ~4 KB LDS, modest VGPR -> one block per CU, co-resident.
    hipLaunchKernelGGL(sim_kernel, dim3(NB), dim3(BS), 0, stream,
                       Rs, sim_dat, sdc, inflow, out);
}

// Round 6
// 629.659 us; speedup vs baseline: 1.7197x; 1.3237x over previous
//
#include <hip/hip_runtime.h>

static constexpr int MM  = 90000;  // cells
static constexpr int TT  = 150;    // steps
static constexpr int BS  = 256;    // threads per block (4 waves)
static constexpr int CPT = 4;      // cells per thread
static constexpr int CPB = BS * CPT;               // 1024 cells per block
static constexpr int NB  = (MM + CPB - 1) / CPB;   // 88 blocks
static constexpr int WPB = BS / 64;                // 4 waves
static constexpr int SLOTS = 128;                  // padded slot row

// Persistent device globals, re-initialized by init_ws_kernel EVERY launch.
// All cross-block traffic: relaxed agent-scope self-flagging words (no fences).
__device__ unsigned int       g_bmax[TT + 1][SLOTS];     // per-block max s bits; [NB..128) = 1u
__device__ unsigned long long g_eAQ[TT + 1][NB][2];      // packed (A,Q) edges; A>=1e-6 => !=0
__device__ unsigned int       g_eF[TT + 1][NB][2];       // edge F_Q bits; F_Q>0 => !=0
__device__ unsigned long long g_dummy64;                 // always nonzero (poll filler)
__device__ unsigned int       g_dummy32;                 // always nonzero

__device__ __forceinline__ float softplus_f(float x) {
    return fmaxf(x, 0.0f) + log1pf(expf(-fabsf(x)));
}
__device__ __forceinline__ unsigned long long packAQ(float A, float Q) {
    return ((unsigned long long)__float_as_uint(Q) << 32) | (unsigned long long)__float_as_uint(A);
}

__global__ void init_ws_kernel() {
    int i = blockIdx.x * blockDim.x + threadIdx.x;
    int stride = gridDim.x * blockDim.x;
    unsigned int* pb = &g_bmax[0][0];
    for (int j = i; j < (TT + 1) * SLOTS; j += stride)
        pb[j] = ((j & (SLOTS - 1)) < NB) ? 0u : 1u;
    unsigned long long* pe = &g_eAQ[0][0][0];
    for (int j = i; j < (TT + 1) * NB * 2; j += stride) pe[j] = 0ull;
    unsigned int* pf = &g_eF[0][0][0];
    for (int j = i; j < (TT + 1) * NB * 2; j += stride) pf[j] = 0u;
    if (i == 0) { g_dummy64 = ~0ull; g_dummy32 = 1u; }
}

__global__ void __launch_bounds__(BS) sim_kernel(
    const float* __restrict__ Rs,
    const float* __restrict__ sim_dat,
    const float* __restrict__ sdc,
    const float* __restrict__ inflow,
    float* __restrict__ out)
{
    __shared__ float sE[2][WPB][2][3];   // [parity][wave][L/R edge cell][A,Q,F] (state_t)
    __shared__ float sred[2][WPB];       // [parity][wave] per-wave max s
    __shared__ float s_smaxv;            // final smax (ordered by __syncthreads)
    __shared__ float s_hL[3], s_hR[3];   // remote halo (A,Q,F)
    __shared__ float s_inflow[TT];

    const int b    = blockIdx.x;
    const int tid  = threadIdx.x;
    const int wv   = tid >> 6;
    const int lane = tid & 63;
    const int base = b * CPB + tid * CPT;   // 4 contiguous cells per thread

    for (int j = tid; j < TT; j += BS) s_inflow[j] = inflow[j];

    // ---- per-cell constants & initial state (registers all sim) ----
    float A[CPT], Q[CPT], A0v[CPT], bet[CPT], cbv[CPT], k2v[CPT], sq[CPT], FQ[CPT];
    bool  act[CPT];
    #pragma unroll
    for (int c = 0; c < CPT; ++c) {
        int i = base + c;
        act[c] = (i < MM);
        if (act[c]) {
            A[c]   = fmaxf(sim_dat[i], 1e-6f);
            Q[c]   = 0.1f * sim_dat[MM + i];
            A0v[c] = sdc[i] + 0.5f;
            bet[c] = sdc[MM + i] + 1.0f;
        } else { A[c] = 1.0f; Q[c] = 0.0f; A0v[c] = 1.0f; bet[c] = 1.0f; }
        cbv[c] = (0.5f * bet[c]) / 1060.0f;     // (0.5*beta)/RHO  (ref op order)
        k2v[c] = bet[c] / (3180.0f * A0v[c]);   // beta/(3*RHO*A0)
    }
    const bool isStart = (base == 0) | (base == 30000) | (base == 60000);                  // cell 0
    const bool isEnd   = (base + 3 == 29999) | (base + 3 == 59999) | (base + 3 == 89999);  // cell 3
    const int midSlot = (base == 15000) ? 0 : (base == 45000) ? 1 : (base == 75000) ? 2 : -1;
    float Rtot = 1.0f;
    if (isEnd) {
        int i3 = base + 3;
        float R1 = sdc[7 * MM + i3] + 0.5f;
        float R2 = sdc[8 * MM + i3] + 0.5f;
        if (i3 == 59999)      { R1 *= softplus_f(Rs[0]); R2 *= softplus_f(Rs[1]); }
        else if (i3 == 89999) { R1 *= softplus_f(Rs[2]); R2 *= softplus_f(Rs[3]); }
        Rtot = R1 + R2;
    }

    const bool pubL = (tid == 0) && (b > 0);            // publish my left edge (read by b-1)
    const bool pubR = (tid == BS - 1) && (b < NB - 1);  // publish my right edge (read by b+1)
    const bool fixL = (tid == 0) && (b > 0);            // my cell0 uses remote left halo
    const bool fixR = (tid == BS - 1) && (b < NB - 1);  // my cell3 uses remote right halo

    // Wave-0 poll-lane pointers (uniform control flow; dummies always nonzero)
    const unsigned long long* pAQ = &g_dummy64;
    const unsigned int*       pF  = &g_dummy32;
    int edgeRole = 0;  // 1 = left AQ, 2 = left F, 3 = right AQ, 4 = right F

    // ---- initial derived state + t=0 publishes ----
    float s4 = 0.0f;
    #pragma unroll
    for (int c = 0; c < CPT; ++c) {
        sq[c] = sqrtf(A[c] / A0v[c]);
        float u  = Q[c] / A[c];
        float cc = sqrtf(cbv[c] * sq[c]);
        FQ[c] = Q[c] * u + k2v[c] * A[c] * sq[c];
        s4 = fmaxf(s4, act[c] ? (fabsf(u) + cc) : 0.0f);
    }
    if (pubL) {
        __hip_atomic_store(&g_eAQ[0][b][0], packAQ(A[0], Q[0]), __ATOMIC_RELAXED, __HIP_MEMORY_SCOPE_AGENT);
        __hip_atomic_store(&g_eF[0][b][0], __float_as_uint(FQ[0]), __ATOMIC_RELAXED, __HIP_MEMORY_SCOPE_AGENT);
    }
    if (pubR) {
        __hip_atomic_store(&g_eAQ[0][b][1], packAQ(A[3], Q[3]), __ATOMIC_RELAXED, __HIP_MEMORY_SCOPE_AGENT);
        __hip_atomic_store(&g_eF[0][b][1], __float_as_uint(FQ[3]), __ATOMIC_RELAXED, __HIP_MEMORY_SCOPE_AGENT);
    }
    {
        float mm = s4;
        #pragma unroll
        for (int off = 32; off > 0; off >>= 1) mm = fmaxf(mm, __shfl_xor(mm, off, 64));
        if (lane == 0)       { sE[0][wv][0][0] = A[0]; sE[0][wv][0][1] = Q[0]; sE[0][wv][0][2] = FQ[0];
                               sred[0][wv] = mm; }
        else if (lane == 63) { sE[0][wv][1][0] = A[3]; sE[0][wv][1][1] = Q[3]; sE[0][wv][1][2] = FQ[3]; }
    }
    if (wv == 0) {   // set up poll roles (wave 0 only)
        if (lane == 0 && b > 0)      { pAQ = &g_eAQ[0][b - 1][1]; edgeRole = 1; }
        if (lane == 1 && b > 0)      { pF  = &g_eF[0][b - 1][1];  edgeRole = 2; }
        if (lane == 2 && b < NB - 1) { pAQ = &g_eAQ[0][b + 1][0]; edgeRole = 3; }
        if (lane == 3 && b < NB - 1) { pF  = &g_eF[0][b + 1][0];  edgeRole = 4; }
    }
    __syncthreads();
    if (wv == 0 && lane == 0) {
        float bm = fmaxf(fmaxf(sred[0][0], sred[0][1]), fmaxf(sred[0][2], sred[0][3]));
        __hip_atomic_store(&g_bmax[0][b], __float_as_uint(bm), __ATOMIC_RELAXED, __HIP_MEMORY_SCOPE_AGENT);
    }

    for (int t = 0; t < TT; ++t) {
        const int par = t & 1, npar = par ^ 1;

        // ===== pre-barrier: neighbor exchange + smax-independent stencil terms =====
        float Am = __shfl_up(A[3], 1, 64),  Qm = __shfl_up(Q[3], 1, 64),  Fm = __shfl_up(FQ[3], 1, 64);
        float Ap = __shfl_down(A[0], 1, 64), Qp = __shfl_down(Q[0], 1, 64), Fp = __shfl_down(FQ[0], 1, 64);
        if (lane == 0 && wv > 0)       { Am = sE[par][wv-1][1][0]; Qm = sE[par][wv-1][1][1]; Fm = sE[par][wv-1][1][2]; }
        if (lane == 63 && wv < WPB - 1){ Ap = sE[par][wv+1][0][0]; Qp = sE[par][wv+1][0][1]; Fp = sE[par][wv+1][0][2]; }

        float dFA[CPT], lapA[CPT], dFQ[CPT], lapQ[CPT];
        #pragma unroll
        for (int c = 0; c < CPT; ++c) {
            float Al = (c == 0) ? Am : A[c-1],  Ql = (c == 0) ? Qm : Q[c-1],  Fl = (c == 0) ? Fm : FQ[c-1];
            float Ar = (c == 3) ? Ap : A[c+1],  Qr = (c == 3) ? Qp : Q[c+1],  Fr = (c == 3) ? Fp : FQ[c+1];
            dFA[c]  = 0.5f * (Qr - Ql);
            lapA[c] = 0.5f * (Ar - 2.0f * A[c] + Al);
            dFQ[c]  = 0.5f * (Fr - Fl);
            lapQ[c] = 0.5f * (Qr - 2.0f * Q[c] + Ql);
        }
        if (midSlot >= 0) out[t * 3 + midSlot] = bet[0] * (sq[0] - 1.0f);
        const float Pend = bet[3] * (sq[3] - 1.0f);   // used only by isEnd threads

        // ===== barrier: wave 0 polls slots + halo words (one parallel batch/iter) =====
        if (wv == 0) {
            const unsigned int* row = &g_bmax[t][0];
            unsigned int x0, x1, xf;
            unsigned long long e64;
            for (;;) {
                x0  = __hip_atomic_load(row + lane,      __ATOMIC_RELAXED, __HIP_MEMORY_SCOPE_AGENT);
                x1  = __hip_atomic_load(row + 64 + lane, __ATOMIC_RELAXED, __HIP_MEMORY_SCOPE_AGENT);
                e64 = __hip_atomic_load(pAQ,             __ATOMIC_RELAXED, __HIP_MEMORY_SCOPE_AGENT);
                xf  = __hip_atomic_load(pF,              __ATOMIC_RELAXED, __HIP_MEMORY_SCOPE_AGENT);
                if (__all((x0 != 0u) & (x1 != 0u) & (e64 != 0ull) & (xf != 0u))) break;
            }
            float ml = fmaxf(__uint_as_float(x0), __uint_as_float(x1));
            #pragma unroll
            for (int off = 32; off > 0; off >>= 1) ml = fmaxf(ml, __shfl_xor(ml, off, 64));
            if (lane == 0) s_smaxv = ml;
            if (edgeRole == 1) { s_hL[0] = __uint_as_float((unsigned int)e64);
                                 s_hL[1] = __uint_as_float((unsigned int)(e64 >> 32)); }
            else if (edgeRole == 2) { s_hL[2] = __uint_as_float(xf); }
            else if (edgeRole == 3) { s_hR[0] = __uint_as_float((unsigned int)e64);
                                      s_hR[1] = __uint_as_float((unsigned int)(e64 >> 32)); }
            else if (edgeRole == 4) { s_hR[2] = __uint_as_float(xf); }
            // advance poll pointers for t+1
            if (edgeRole == 1) pAQ = &g_eAQ[t + 1][b - 1][1];
            else if (edgeRole == 2) pF = &g_eF[t + 1][b - 1][1];
            else if (edgeRole == 3) pAQ = &g_eAQ[t + 1][b + 1][0];
            else if (edgeRole == 4) pF = &g_eF[t + 1][b + 1][0];
        }
        __syncthreads();

        // ===== post-barrier: tiny smax-dependent tail =====
        const float smax = s_smaxv;
        const float dt  = ((float)(0.9 * 0.001)) / smax;   // ref op order
        const float lam = dt / 0.001f;
        const float w   = lam * smax;

        if (fixL) {   // cell 0 stencil terms from remote halo
            float Al = s_hL[0], Ql = s_hL[1], Fl = s_hL[2];
            dFA[0]  = 0.5f * (Q[1] - Ql);
            lapA[0] = 0.5f * (A[1] - 2.0f * A[0] + Al);
            dFQ[0]  = 0.5f * (FQ[1] - Fl);
            lapQ[0] = 0.5f * (Q[1] - 2.0f * Q[0] + Ql);
        }
        if (fixR) {   // cell 3 stencil terms from remote halo
            float Ar = s_hR[0], Qr = s_hR[1], Fr = s_hR[2];
            dFA[3]  = 0.5f * (Qr - Q[2]);
            lapA[3] = 0.5f * (Ar - 2.0f * A[3] + A[2]);
            dFQ[3]  = 0.5f * (Fr - FQ[2]);
            lapQ[3] = 0.5f * (Qr - 2.0f * Q[3] + Q[2]);
        }
        #pragma unroll
        for (int c = 0; c < CPT; ++c) {
            int i = base + c;
            if (act[c] && i > 0 && i < MM - 1) {
                A[c] = fmaf(w, lapA[c], fmaf(-lam, dFA[c], A[c]));
                Q[c] = fmaf(w, lapQ[c], fmaf(-lam, dFQ[c], Q[c]));
            }
        }
        if (isStart) Q[0] = s_inflow[t];
        if (isEnd)   Q[3] = Pend / Rtot;
        #pragma unroll
        for (int c = 0; c < CPT; ++c) A[c] = fmaxf(A[c], 1e-6f);

        // publish t+1 edges ASAP (AQ now, F after derived)
        if (pubL) __hip_atomic_store(&g_eAQ[t+1][b][0], packAQ(A[0], Q[0]), __ATOMIC_RELAXED, __HIP_MEMORY_SCOPE_AGENT);
        if (pubR) __hip_atomic_store(&g_eAQ[t+1][b][1], packAQ(A[3], Q[3]), __ATOMIC_RELAXED, __HIP_MEMORY_SCOPE_AGENT);

        // derived state for t+1 + wave max
        s4 = 0.0f;
        #pragma unroll
        for (int c = 0; c < CPT; ++c) {
            sq[c] = sqrtf(A[c] / A0v[c]);
            float u  = Q[c] / A[c];
            float cc = sqrtf(cbv[c] * sq[c]);
            FQ[c] = Q[c] * u + k2v[c] * A[c] * sq[c];
            s4 = fmaxf(s4, act[c] ? (fabsf(u) + cc) : 0.0f);
        }
        if (pubL) __hip_atomic_store(&g_eF[t+1][b][0], __float_as_uint(FQ[0]), __ATOMIC_RELAXED, __HIP_MEMORY_SCOPE_AGENT);
        if (pubR) __hip_atomic_store(&g_eF[t+1][b][1], __float_as_uint(FQ[3]), __ATOMIC_RELAXED, __HIP_MEMORY_SCOPE_AGENT);

        float mm = s4;
        #pragma unroll
        for (int off = 32; off > 0; off >>= 1) mm = fmaxf(mm, __shfl_xor(mm, off, 64));
        if (lane == 0)       { sE[npar][wv][0][0] = A[0]; sE[npar][wv][0][1] = Q[0]; sE[npar][wv][0][2] = FQ[0];
                               sred[npar][wv] = mm; }
        else if (lane == 63) { sE[npar][wv][1][0] = A[3]; sE[npar][wv][1][1] = Q[3]; sE[npar][wv][1][2] = FQ[3]; }
        __syncthreads();

        if (wv == 0 && lane == 0) {
            float bm = fmaxf(fmaxf(sred[npar][0], sred[npar][1]), fmaxf(sred[npar][2], sred[npar][3]));
            __hip_atomic_store(&g_bmax[t + 1][b], __float_as_uint(bm), __ATOMIC_RELAXED, __HIP_MEMORY_SCOPE_AGENT);
        }
    }
}

extern "C" void kernel_launch(void* const* d_in, const int* in_sizes, int n_in,
                              void* d_out, int out_size, void* d_ws, size_t ws_size,
                              hipStream_t stream) {
    (void)in_sizes; (void)n_in; (void)d_ws; (void)ws_size; (void)out_size;

    const float* Rs      = (const float*)d_in[0];
    const float* sim_dat = (const float*)d_in[1];
    const float* sdc     = (const float*)d_in[2];
    const float* inflow  = (const float*)d_in[3];
    float* out = (float*)d_out;

    hipLaunchKernelGGL(init_ws_kernel, dim3(120), dim3(256), 0, stream);

    // 88 blocks x 4 waves, ~2 KB LDS -> trivially co-resident on 256 CUs.
    hipLaunchKernelGGL(sim_kernel, dim3(NB), dim3(BS), 0, stream,
                       Rs, sim_dat, sdc, inflow, out);
}

// Round 7
// 623.210 us; speedup vs baseline: 1.7375x; 1.0103x over previous
//
#include <hip/hip_runtime.h>

static constexpr int MM  = 90000;  // cells
static constexpr int TT  = 150;    // steps
static constexpr int BS  = 256;    // threads per block (4 waves)
static constexpr int CPT = 4;      // cells per thread
static constexpr int CPB = BS * CPT;               // 1024 cells per block
static constexpr int NB  = (MM + CPB - 1) / CPB;   // 88 blocks
static constexpr int WPB = BS / 64;                // 4 waves
static constexpr int SLOTS = 128;                  // padded block-slot row (master-polled only)

// Persistent device globals, re-initialized by init_ws_kernel EVERY launch.
// Cross-block traffic: relaxed agent-scope self-flagging words (no fences).
__device__ unsigned int       g_bmax[TT + 1][SLOTS];   // per-block max s bits; [NB..128)=1u (master-only readers)
__device__ unsigned int       g_smax[TT + 1][16];      // [t][0] = final smax bits; one 64B line per step
__device__ __align__(64) unsigned long long g_edge[TT + 1][NB][2][2];  // [t][b][L/R][AQ, F] 16B co-located

__device__ __forceinline__ float softplus_f(float x) {
    return fmaxf(x, 0.0f) + log1pf(expf(-fabsf(x)));
}
__device__ __forceinline__ unsigned long long packAQ(float A, float Q) {
    return ((unsigned long long)__float_as_uint(Q) << 32) | (unsigned long long)__float_as_uint(A);
}
#define AG_LOAD32(p)     __hip_atomic_load((p), __ATOMIC_RELAXED, __HIP_MEMORY_SCOPE_AGENT)
#define AG_LOAD64(p)     __hip_atomic_load((p), __ATOMIC_RELAXED, __HIP_MEMORY_SCOPE_AGENT)
#define AG_STORE32(p, v) __hip_atomic_store((p), (v), __ATOMIC_RELAXED, __HIP_MEMORY_SCOPE_AGENT)
#define AG_STORE64(p, v) __hip_atomic_store((p), (v), __ATOMIC_RELAXED, __HIP_MEMORY_SCOPE_AGENT)

__global__ void init_ws_kernel() {
    int i = blockIdx.x * blockDim.x + threadIdx.x;
    int stride = gridDim.x * blockDim.x;
    unsigned int* pb = &g_bmax[0][0];
    for (int j = i; j < (TT + 1) * SLOTS; j += stride)
        pb[j] = ((j & (SLOTS - 1)) < NB) ? 0u : 1u;
    unsigned int* ps = &g_smax[0][0];
    for (int j = i; j < (TT + 1) * 16; j += stride) ps[j] = 0u;
    unsigned long long* pe = &g_edge[0][0][0][0];
    for (int j = i; j < (TT + 1) * NB * 2 * 2; j += stride) pe[j] = 0ull;
}

__global__ void __launch_bounds__(BS) sim_kernel(
    const float* __restrict__ Rs,
    const float* __restrict__ sim_dat,
    const float* __restrict__ sdc,
    const float* __restrict__ inflow,
    float* __restrict__ out)
{
    __shared__ float sE[2][WPB][2][3];   // [parity][wave][L/R edge cell][A,Q,F] (state_t)
    __shared__ float sred[2][WPB];       // [parity][wave] per-wave max s
    __shared__ float s_smaxv;            // final smax (ordered by __syncthreads)
    __shared__ float s_hL[3], s_hR[3];   // remote halo (A,Q,F)
    __shared__ float s_inflow[TT];

    const int b    = blockIdx.x;
    const int tid  = threadIdx.x;
    const int wv   = tid >> 6;
    const int lane = tid & 63;
    const int base = b * CPB + tid * CPT;   // 4 contiguous cells per thread

    for (int j = tid; j < TT; j += BS) s_inflow[j] = inflow[j];

    // ---- per-cell constants & initial state (registers all sim) ----
    float A[CPT], Q[CPT], A0v[CPT], bet[CPT], cbv[CPT], k2v[CPT], sq[CPT], FQ[CPT];
    bool  act[CPT];
    #pragma unroll
    for (int c = 0; c < CPT; ++c) {
        int i = base + c;
        act[c] = (i < MM);
        if (act[c]) {
            A[c]   = fmaxf(sim_dat[i], 1e-6f);
            Q[c]   = 0.1f * sim_dat[MM + i];
            A0v[c] = sdc[i] + 0.5f;
            bet[c] = sdc[MM + i] + 1.0f;
        } else { A[c] = 1.0f; Q[c] = 0.0f; A0v[c] = 1.0f; bet[c] = 1.0f; }
        cbv[c] = (0.5f * bet[c]) / 1060.0f;     // (0.5*beta)/RHO  (ref op order)
        k2v[c] = bet[c] / (3180.0f * A0v[c]);   // beta/(3*RHO*A0)
    }
    const bool isStart = (base == 0) | (base == 30000) | (base == 60000);                  // cell 0
    const bool isEnd   = (base + 3 == 29999) | (base + 3 == 59999) | (base + 3 == 89999);  // cell 3
    const int midSlot = (base == 15000) ? 0 : (base == 45000) ? 1 : (base == 75000) ? 2 : -1;
    float Rtot = 1.0f;
    if (isEnd) {
        int i3 = base + 3;
        float R1 = sdc[7 * MM + i3] + 0.5f;
        float R2 = sdc[8 * MM + i3] + 0.5f;
        if (i3 == 59999)      { R1 *= softplus_f(Rs[0]); R2 *= softplus_f(Rs[1]); }
        else if (i3 == 89999) { R1 *= softplus_f(Rs[2]); R2 *= softplus_f(Rs[3]); }
        Rtot = R1 + R2;
    }

    const bool pubL = (tid == 0) && (b > 0);            // publish my left edge (read by b-1)
    const bool pubR = (tid == BS - 1) && (b < NB - 1);  // publish my right edge (read by b+1)
    const bool fixL = (tid == 0) && (b > 0);            // my cell0 uses remote left halo
    const bool fixR = (tid == BS - 1) && (b < NB - 1);  // my cell3 uses remote right halo

    // ---- initial derived state + t=0 publishes ----
    float s4 = 0.0f;
    #pragma unroll
    for (int c = 0; c < CPT; ++c) {
        sq[c] = sqrtf(A[c] / A0v[c]);
        float u  = Q[c] / A[c];
        float cc = sqrtf(cbv[c] * sq[c]);
        FQ[c] = Q[c] * u + k2v[c] * A[c] * sq[c];
        s4 = fmaxf(s4, act[c] ? (fabsf(u) + cc) : 0.0f);
    }
    if (pubL) {
        AG_STORE64(&g_edge[0][b][0][0], packAQ(A[0], Q[0]));
        AG_STORE64(&g_edge[0][b][0][1], (unsigned long long)__float_as_uint(FQ[0]));
    }
    if (pubR) {
        AG_STORE64(&g_edge[0][b][1][0], packAQ(A[3], Q[3]));
        AG_STORE64(&g_edge[0][b][1][1], (unsigned long long)__float_as_uint(FQ[3]));
    }
    {
        float mm = s4;
        #pragma unroll
        for (int off = 32; off > 0; off >>= 1) mm = fmaxf(mm, __shfl_xor(mm, off, 64));
        if (lane == 0)       { sE[0][wv][0][0] = A[0]; sE[0][wv][0][1] = Q[0]; sE[0][wv][0][2] = FQ[0];
                               sred[0][wv] = mm; }
        else if (lane == 63) { sE[0][wv][1][0] = A[3]; sE[0][wv][1][1] = Q[3]; sE[0][wv][1][2] = FQ[3]; }
    }
    __syncthreads();
    if (wv == 0 && lane == 0) {
        float bm = fmaxf(fmaxf(sred[0][0], sred[0][1]), fmaxf(sred[0][2], sred[0][3]));
        AG_STORE32(&g_bmax[0][b], __float_as_uint(bm));
    }

    for (int t = 0; t < TT; ++t) {
        const int par = t & 1, npar = par ^ 1;

        // ===== pre-barrier: neighbor exchange + smax-independent stencil terms =====
        float Am = __shfl_up(A[3], 1, 64),  Qm = __shfl_up(Q[3], 1, 64),  Fm = __shfl_up(FQ[3], 1, 64);
        float Ap = __shfl_down(A[0], 1, 64), Qp = __shfl_down(Q[0], 1, 64), Fp = __shfl_down(FQ[0], 1, 64);
        if (lane == 0 && wv > 0)       { Am = sE[par][wv-1][1][0]; Qm = sE[par][wv-1][1][1]; Fm = sE[par][wv-1][1][2]; }
        if (lane == 63 && wv < WPB - 1){ Ap = sE[par][wv+1][0][0]; Qp = sE[par][wv+1][0][1]; Fp = sE[par][wv+1][0][2]; }

        float dFA[CPT], lapA[CPT], dFQ[CPT], lapQ[CPT];
        #pragma unroll
        for (int c = 0; c < CPT; ++c) {
            float Al = (c == 0) ? Am : A[c-1],  Ql = (c == 0) ? Qm : Q[c-1],  Fl = (c == 0) ? Fm : FQ[c-1];
            float Ar = (c == 3) ? Ap : A[c+1],  Qr = (c == 3) ? Qp : Q[c+1],  Fr = (c == 3) ? Fp : FQ[c+1];
            dFA[c]  = 0.5f * (Qr - Ql);
            lapA[c] = 0.5f * (Ar - 2.0f * A[c] + Al);
            dFQ[c]  = 0.5f * (Fr - Fl);
            lapQ[c] = 0.5f * (Qr - 2.0f * Q[c] + Ql);
        }
        if (midSlot >= 0) out[t * 3 + midSlot] = bet[0] * (sq[0] - 1.0f);
        const float Pend = bet[3] * (sq[3] - 1.0f);   // used only by isEnd threads

        // ===== barrier =====
        if (wv == 0) {
            if (b == 0) {
                // ---- master: sole poller of the 88-slot row; publishes g_smax[t] ----
                const unsigned int* row = &g_bmax[t][0];
                unsigned int x0, x1;
                unsigned long long eR0 = 1ull, eR1 = 1ull;
                for (;;) {
                    x0 = AG_LOAD32(row + lane);
                    x1 = AG_LOAD32(row + 64 + lane);
                    bool ok = (x0 != 0u) & (x1 != 0u);
                    if (lane == 2) {   // b==0 always has a right neighbor (NB>1)
                        eR0 = AG_LOAD64(&g_edge[t][1][0][0]);
                        eR1 = AG_LOAD64(&g_edge[t][1][0][1]);
                        ok &= (eR0 != 0ull) & (eR1 != 0ull);
                    }
                    if (__all(ok)) break;
                }
                float ml = fmaxf(__uint_as_float(x0), __uint_as_float(x1));
                #pragma unroll
                for (int off = 32; off > 0; off >>= 1) ml = fmaxf(ml, __shfl_xor(ml, off, 64));
                if (lane == 0) {
                    AG_STORE32(&g_smax[t][0], __float_as_uint(ml));
                    s_smaxv = ml;
                }
                if (lane == 2) {
                    s_hR[0] = __uint_as_float((unsigned int)eR0);
                    s_hR[1] = __uint_as_float((unsigned int)(eR0 >> 32));
                    s_hR[2] = __uint_as_float((unsigned int)eR1);
                }
            } else {
                // ---- follower: poll ONE word (+ own halo slots); gentle backoff ----
                unsigned int sm;
                unsigned long long eL0 = 1ull, eL1 = 1ull, eR0 = 1ull, eR1 = 1ull;
                for (;;) {
                    sm = AG_LOAD32(&g_smax[t][0]);   // 64 same-address lanes -> 1 request
                    bool ok = (sm != 0u);
                    if (lane == 1) {
                        eL0 = AG_LOAD64(&g_edge[t][b - 1][1][0]);
                        eL1 = AG_LOAD64(&g_edge[t][b - 1][1][1]);
                        ok &= (eL0 != 0ull) & (eL1 != 0ull);
                    }
                    if (lane == 2 && b < NB - 1) {
                        eR0 = AG_LOAD64(&g_edge[t][b + 1][0][0]);
                        eR1 = AG_LOAD64(&g_edge[t][b + 1][0][1]);
                        ok &= (eR0 != 0ull) & (eR1 != 0ull);
                    }
                    if (__all(ok)) break;
                    __builtin_amdgcn_s_sleep(1);     // keep the shared line un-hammered
                }
                if (lane == 0) s_smaxv = __uint_as_float(sm);
                if (lane == 1) {
                    s_hL[0] = __uint_as_float((unsigned int)eL0);
                    s_hL[1] = __uint_as_float((unsigned int)(eL0 >> 32));
                    s_hL[2] = __uint_as_float((unsigned int)eL1);
                }
                if (lane == 2 && b < NB - 1) {
                    s_hR[0] = __uint_as_float((unsigned int)eR0);
                    s_hR[1] = __uint_as_float((unsigned int)(eR0 >> 32));
                    s_hR[2] = __uint_as_float((unsigned int)eR1);
                }
            }
        }
        __syncthreads();

        // ===== post-barrier: tiny smax-dependent tail =====
        const float smax = s_smaxv;
        const float dt  = ((float)(0.9 * 0.001)) / smax;   // ref op order
        const float lam = dt / 0.001f;
        const float w   = lam * smax;

        if (fixL) {   // cell 0 stencil terms from remote halo
            float Al = s_hL[0], Ql = s_hL[1], Fl = s_hL[2];
            dFA[0]  = 0.5f * (Q[1] - Ql);
            lapA[0] = 0.5f * (A[1] - 2.0f * A[0] + Al);
            dFQ[0]  = 0.5f * (FQ[1] - Fl);
            lapQ[0] = 0.5f * (Q[1] - 2.0f * Q[0] + Ql);
        }
        if (fixR) {   // cell 3 stencil terms from remote halo
            float Ar = s_hR[0], Qr = s_hR[1], Fr = s_hR[2];
            dFA[3]  = 0.5f * (Qr - Q[2]);
            lapA[3] = 0.5f * (Ar - 2.0f * A[3] + A[2]);
            dFQ[3]  = 0.5f * (Fr - FQ[2]);
            lapQ[3] = 0.5f * (Qr - 2.0f * Q[3] + Q[2]);
        }
        #pragma unroll
        for (int c = 0; c < CPT; ++c) {
            int i = base + c;
            if (act[c] && i > 0 && i < MM - 1) {
                A[c] = fmaf(w, lapA[c], fmaf(-lam, dFA[c], A[c]));
                Q[c] = fmaf(w, lapQ[c], fmaf(-lam, dFQ[c], Q[c]));
            }
        }
        if (isStart) Q[0] = s_inflow[t];
        if (isEnd)   Q[3] = Pend / Rtot;
        #pragma unroll
        for (int c = 0; c < CPT; ++c) A[c] = fmaxf(A[c], 1e-6f);

        // publish t+1 edges ASAP (AQ now, F after derived)
        if (pubL) AG_STORE64(&g_edge[t+1][b][0][0], packAQ(A[0], Q[0]));
        if (pubR) AG_STORE64(&g_edge[t+1][b][1][0], packAQ(A[3], Q[3]));

        // derived state for t+1 + wave max
        s4 = 0.0f;
        #pragma unroll
        for (int c = 0; c < CPT; ++c) {
            sq[c] = sqrtf(A[c] / A0v[c]);
            float u  = Q[c] / A[c];
            float cc = sqrtf(cbv[c] * sq[c]);
            FQ[c] = Q[c] * u + k2v[c] * A[c] * sq[c];
            s4 = fmaxf(s4, act[c] ? (fabsf(u) + cc) : 0.0f);
        }
        if (pubL) AG_STORE64(&g_edge[t+1][b][0][1], (unsigned long long)__float_as_uint(FQ[0]));
        if (pubR) AG_STORE64(&g_edge[t+1][b][1][1], (unsigned long long)__float_as_uint(FQ[3]));

        float mm = s4;
        #pragma unroll
        for (int off = 32; off > 0; off >>= 1) mm = fmaxf(mm, __shfl_xor(mm, off, 64));
        if (lane == 0)       { sE[npar][wv][0][0] = A[0]; sE[npar][wv][0][1] = Q[0]; sE[npar][wv][0][2] = FQ[0];
                               sred[npar][wv] = mm; }
        else if (lane == 63) { sE[npar][wv][1][0] = A[3]; sE[npar][wv][1][1] = Q[3]; sE[npar][wv][1][2] = FQ[3]; }
        __syncthreads();

        if (wv == 0 && lane == 0) {
            float bm = fmaxf(fmaxf(sred[npar][0], sred[npar][1]), fmaxf(sred[npar][2], sred[npar][3]));
            AG_STORE32(&g_bmax[t + 1][b], __float_as_uint(bm));
        }
    }
}

extern "C" void kernel_launch(void* const* d_in, const int* in_sizes, int n_in,
                              void* d_out, int out_size, void* d_ws, size_t ws_size,
                              hipStream_t stream) {
    (void)in_sizes; (void)n_in; (void)d_ws; (void)ws_size; (void)out_size;

    const float* Rs      = (const float*)d_in[0];
    const float* sim_dat = (const float*)d_in[1];
    const float* sdc     = (const float*)d_in[2];
    const float* inflow  = (const float*)d_in[3];
    float* out = (float*)d_out;

    hipLaunchKernelGGL(init_ws_kernel, dim3(120), dim3(256), 0, stream);

    // 88 blocks x 4 waves, ~2 KB LDS -> trivially co-resident on 256 CUs.
    hipLaunchKernelGGL(sim_kernel, dim3(NB), dim3(BS), 0, stream,
                       Rs, sim_dat, sdc, inflow, out);
}